// Round 14
// baseline (465.655 us; speedup 1.0000x reference)
//
#include <hip/hip_runtime.h>
#include <hip/hip_fp16.h>

#define N_NODES   100000
#define N_EDGES   1600000
#define NUM_GRAPHS 128
#define HID       64

#define NB   512          // buckets (node-space partitions)
#define NPB  196          // nodes per bucket
#define NBU  511          // used buckets
#define CPE  3125         // edges per binning chunk
#define CSR_TOT (N_EDGES + N_NODES)   // CSR includes one self entry per node

#define SLICES 4
#define FPS 16                         // features per slice; slice = 3.2MB < 4MB XCD L2
#define PASS_CHUNKS ((N_NODES + 63) / 64)   // 1563 chunks of 64 nodes per pass
// sliced feature layout: t[p][v][f]
#define SL(p, v, f) (((size_t)(p) * N_NODES + (v)) * FPS + (f))

// ---------------------------------------------------------------- bucketed CSR build

__global__ __launch_bounds__(256) void k_b1a(const int* __restrict__ dst, int* __restrict__ H) {
  __shared__ int hist[NB];
  int w = blockIdx.x, t = threadIdx.x;
  for (int b = t; b < NB; b += 256) hist[b] = 0;
  __syncthreads();
  int e0 = w * CPE;
  for (int i = t; i < CPE; i += 256)
    atomicAdd(&hist[dst[e0 + i] / NPB], 1);
  __syncthreads();
  for (int b = t; b < NB; b += 256) H[w * NB + b] = hist[b];
}

__global__ __launch_bounds__(256) void k_colsum(const int* __restrict__ H, int* __restrict__ S) {
  __shared__ int red[256];
  int b = blockIdx.x, t = threadIdx.x;
  red[t] = H[t * NB + b] + H[(t + 256) * NB + b];
  __syncthreads();
  for (int d = 128; d > 0; d >>= 1) { if (t < d) red[t] += red[t + d]; __syncthreads(); }
  if (t == 0) S[b] = red[0];
}

__global__ __launch_bounds__(512) void k_rowscan(const int* __restrict__ H,
                                                 const int* __restrict__ S,
                                                 int* __restrict__ bstart,
                                                 int* __restrict__ OT,
                                                 int* __restrict__ dbins) {
  __shared__ int sb[NB];
  __shared__ int sc[NB];
  int b = blockIdx.x, t = threadIdx.x;
  if (t < 256) dbins[t] = 0;
  int sv = S[t];
  sb[t] = sv; __syncthreads();
  for (int d = 1; d < NB; d <<= 1) {
    int x = (t >= d) ? sb[t - d] : 0; __syncthreads();
    sb[t] += x; __syncthreads();
  }
  int bst = sb[b] - S[b];
  if (t == 0) bstart[b] = bst;
  if (b == NB - 1 && t == 0) bstart[NB] = sb[NB - 1];
  int v = H[t * NB + b];
  sc[t] = v; __syncthreads();
  for (int d = 1; d < NB; d <<= 1) {
    int x = (t >= d) ? sc[t - d] : 0; __syncthreads();
    sc[t] += x; __syncthreads();
  }
  OT[b * NB + t] = bst + sc[t] - v;
}

__global__ __launch_bounds__(256) void k_b1b(const int* __restrict__ src,
                                             const int* __restrict__ dst,
                                             const int* __restrict__ OT,
                                             int2* __restrict__ staged) {
  __shared__ int pos[NB];
  int w = blockIdx.x, t = threadIdx.x;
  for (int b = t; b < NB; b += 256) pos[b] = OT[b * NB + w];
  __syncthreads();
  int e0 = w * CPE;
  for (int i = t; i < CPE; i += 256) {
    int s = src[e0 + i], d = dst[e0 + i];
    int p = atomicAdd(&pos[d / NPB], 1);
    staged[p] = make_int2(s, d);
  }
}

// B2a: LDS node counts -> monotone row_off + dinv + LDS-aggregated degree hist (ascending).
__global__ __launch_bounds__(256) void k_b2a(const int2* __restrict__ staged,
                                             const int* __restrict__ bstart,
                                             int* __restrict__ row_off,
                                             float* __restrict__ dinv,
                                             int* __restrict__ dbins) {
  __shared__ int cnt[256];
  __shared__ int sc[256];
  __shared__ int hb[256];
  int b = blockIdx.x, t = threadIdx.x;
  int nloc = min(NPB, N_NODES - b * NPB);
  cnt[t] = 0;
  hb[t] = 0;
  __syncthreads();
  int s0 = bstart[b], s1 = bstart[b + 1];
  for (int i = s0 + t; i < s1; i += 256)
    atomicAdd(&cnt[staged[i].y - b * NPB], 1);
  __syncthreads();
  if (t < nloc) atomicAdd(&hb[min(cnt[t] + 1, 255)], 1);
  int v = (t < nloc) ? cnt[t] + 1 : 0;
  sc[t] = v; __syncthreads();
  for (int d = 1; d < 256; d <<= 1) {
    int x = (t >= d) ? sc[t - d] : 0; __syncthreads();
    sc[t] += x; __syncthreads();
  }
  if (t < nloc) {
    int g = b * NPB + t;
    row_off[g] = bstart[b] + b * NPB + (sc[t] - v);
    dinv[g] = rsqrtf((float)(cnt[t] + 1));
  }
  __syncthreads();
  if (hb[t] > 0) atomicAdd(&dbins[t], hb[t]);
  if (b == 0 && t == 0) row_off[N_NODES] = CSR_TOT;
}

// 4B CSR entry: src (17 bits) << 15 | fp16(norm) sans sign (15 bits). norm>0.
__device__ __forceinline__ unsigned int enc_csr(int s, float n) {
  unsigned short bits = __half_as_ushort(__float2half_rn(n));
  return ((unsigned int)s << 15) | (unsigned int)(bits & 0x7fff);
}

__global__ __launch_bounds__(256) void k_b2b(const int2* __restrict__ staged,
                                             const int* __restrict__ bstart,
                                             const int* __restrict__ row_off,
                                             const float* __restrict__ dinv,
                                             unsigned int* __restrict__ csr4) {
  __shared__ int pos[NPB];
  __shared__ float dl[NPB];
  int b = blockIdx.x, t = threadIdx.x;
  int nloc = min(NPB, N_NODES - b * NPB);
  if (t < nloc) {
    int g = b * NPB + t;
    int ro = row_off[g];
    float dv = dinv[g];
    csr4[ro] = enc_csr(g, dv * dv);   // self-loop entry
    pos[t] = ro + 1;
    dl[t] = dv;
  }
  __syncthreads();
  int s0 = bstart[b], s1 = bstart[b + 1];
  for (int i = s0 + t; i < s1; i += 256) {
    int2 e = staged[i];
    int l = e.y - b * NPB;
    int p = atomicAdd(&pos[l], 1);
    csr4[p] = enc_csr(e.x, dl[l] * dinv[e.x]);
  }
}

// ---------------------------------------------------------------- degree sort (ascending)
// dscan also zeroes pooled/pcnt and the 12 per-layer pass queues.

__global__ __launch_bounds__(256) void k_dscan(const int* __restrict__ dbins,
                                               int* __restrict__ dpos,
                                               float* __restrict__ pooled,
                                               int* __restrict__ pcnt,
                                               int* __restrict__ qcnt) {
  __shared__ int sc[256];
  int t = threadIdx.x;
  #pragma unroll
  for (int i = 0; i < 32; ++i) pooled[i * 256 + t] = 0.f;
  if (t < 128) pcnt[t] = 0;
  if (t < 12) qcnt[t] = 0;
  int v = dbins[t];
  sc[t] = v; __syncthreads();
  for (int d = 1; d < 256; d <<= 1) {
    int x = (t >= d) ? sc[t - d] : 0; __syncthreads();
    sc[t] += x; __syncthreads();
  }
  dpos[t] = sc[t] - v;
}

__global__ __launch_bounds__(256) void k_dperm(const int* __restrict__ row_off,
                                               int* __restrict__ dpos,
                                               int* __restrict__ perm) {
  __shared__ int cnt[256];
  __shared__ int sbase[256];
  int t = threadIdx.x;
  cnt[t] = 0;
  __syncthreads();
  int v = blockIdx.x * 256 + t;
  int bin = 0, rank = 0;
  if (v < N_NODES) {
    bin = min(row_off[v + 1] - row_off[v], 255);   // ascending
    rank = atomicAdd(&cnt[bin], 1);
  }
  __syncthreads();
  if (cnt[t] > 0) sbase[t] = atomicAdd(&dpos[t], cnt[t]);
  __syncthreads();
  if (v < N_NODES) perm[sbase[bin] + rank] = v;
}

// ---------------------------------------------------------------- dense GEMM (sliced out)
// layer 1 reads f32 input row-major; layers 2-3 read sliced fp16.

__device__ __forceinline__ void gemm_core_and_store(float sA[64][65], float* sW,
                                                    __half* __restrict__ C, int row0) {
  int tid = threadIdx.x;
  int tr = (tid >> 4) << 2;
  int tc = (tid & 15) << 2;
  float acc[4][4];
  #pragma unroll
  for (int i = 0; i < 4; ++i)
    #pragma unroll
    for (int j = 0; j < 4; ++j) acc[i][j] = 0.f;
  #pragma unroll 8
  for (int k = 0; k < 64; ++k) {
    float4 w = *(const float4*)&sW[k * 64 + tc];
    float a0 = sA[tr + 0][k], a1 = sA[tr + 1][k], a2 = sA[tr + 2][k], a3 = sA[tr + 3][k];
    acc[0][0] += a0 * w.x; acc[0][1] += a0 * w.y; acc[0][2] += a0 * w.z; acc[0][3] += a0 * w.w;
    acc[1][0] += a1 * w.x; acc[1][1] += a1 * w.y; acc[1][2] += a1 * w.z; acc[1][3] += a1 * w.w;
    acc[2][0] += a2 * w.x; acc[2][1] += a2 * w.y; acc[2][2] += a2 * w.z; acc[2][3] += a2 * w.w;
    acc[3][0] += a3 * w.x; acc[3][1] += a3 * w.y; acc[3][2] += a3 * w.z; acc[3][3] += a3 * w.w;
  }
  #pragma unroll
  for (int i = 0; i < 4; ++i) {
    int row = row0 + tr + i;
    if (row < N_NODES) {
      __half* c = C + SL(tc >> 4, row, tc & 15);
      ((__half2*)c)[0] = __floats2half2_rn(acc[i][0], acc[i][1]);
      ((__half2*)c)[1] = __floats2half2_rn(acc[i][2], acc[i][3]);
    }
  }
}

__global__ __launch_bounds__(256) void k_gemm_f32(const float* __restrict__ A,
                                                  const float* __restrict__ W,
                                                  __half* __restrict__ C) {
  __shared__ float sW[64 * 64];
  __shared__ float sA[64][65];
  int tid = threadIdx.x;
  #pragma unroll
  for (int i = tid; i < 1024; i += 256)
    ((float4*)sW)[i] = ((const float4*)W)[i];
  int row0 = blockIdx.x * 64;
  #pragma unroll
  for (int i = tid; i < 1024; i += 256) {
    int r = i >> 4, c4 = (i & 15) << 2;
    int row = row0 + r;
    if (row < N_NODES) {
      float4 v = *(const float4*)(A + (size_t)row * 64 + c4);
      sA[r][c4 + 0] = v.x; sA[r][c4 + 1] = v.y; sA[r][c4 + 2] = v.z; sA[r][c4 + 3] = v.w;
    } else {
      sA[r][c4 + 0] = 0.f; sA[r][c4 + 1] = 0.f; sA[r][c4 + 2] = 0.f; sA[r][c4 + 3] = 0.f;
    }
  }
  __syncthreads();
  gemm_core_and_store(sA, sW, C, row0);
}

__global__ __launch_bounds__(256) void k_gemm(const __half* __restrict__ A,
                                              const float* __restrict__ W,
                                              __half* __restrict__ C) {
  __shared__ float sW[64 * 64];
  __shared__ float sA[64][65];
  int tid = threadIdx.x;
  #pragma unroll
  for (int i = tid; i < 1024; i += 256)
    ((float4*)sW)[i] = ((const float4*)W)[i];
  int row0 = blockIdx.x * 64;
  #pragma unroll
  for (int i = tid; i < 1024; i += 256) {
    int r = i >> 4, c4 = (i & 15) << 2;
    int row = row0 + r;
    if (row < N_NODES) {
      const __half* a = A + SL(c4 >> 4, row, c4 & 15);
      float2 fa = __half22float2(((const __half2*)a)[0]);
      float2 fb = __half22float2(((const __half2*)a)[1]);
      sA[r][c4 + 0] = fa.x; sA[r][c4 + 1] = fa.y;
      sA[r][c4 + 2] = fb.x; sA[r][c4 + 3] = fb.y;
    } else {
      sA[r][c4 + 0] = 0.f; sA[r][c4 + 1] = 0.f; sA[r][c4 + 2] = 0.f; sA[r][c4 + 3] = 0.f;
    }
  }
  __syncthreads();
  gemm_core_and_store(sA, sW, C, row0);
}

// ---------------------------------------------------------------- XCD-pinned sliced aggregation
// 4 feature-slice passes; a block SELF-IDENTIFIES its XCD (s_getreg XCC_ID,
// HW-verified on gfx950) and pulls a 64-node chunk from its own pass's queue,
// so each XCD's L2 only ever gathers from its resident 3.2MB slice. Overflow
// falls through to other passes (provably covers all 4*1563 chunks).
// Geometry: 16 nodes/wave (degree-sorted ASC), 4 lanes/node, 8B/lane, unroll 8.
// CSR loads PLAIN (R12 lesson); out stores NT (keep slice resident).

__device__ __forceinline__ void fma4(float* acc, float n, uint2 h) {
  float2 f0 = __half22float2(*(__half2*)&h.x);
  float2 f1 = __half22float2(*(__half2*)&h.y);
  acc[0] = fmaf(n, f0.x, acc[0]); acc[1] = fmaf(n, f0.y, acc[1]);
  acc[2] = fmaf(n, f1.x, acc[2]); acc[3] = fmaf(n, f1.y, acc[3]);
}

__device__ __forceinline__ float dec_norm(unsigned int e) {
  return __half2float(__ushort_as_half((unsigned short)(e & 0x7fffu)));
}

__global__ __launch_bounds__(256) void k_aggs(const __half* __restrict__ hs,
                                              const int* __restrict__ row_off,
                                              const unsigned int* __restrict__ csr4,
                                              const int* __restrict__ perm,
                                              const float* __restrict__ bias,
                                              __half* __restrict__ outs,
                                              int* __restrict__ q) {
  __shared__ int sChunk, sPass;
  if (threadIdx.x == 0) {
    unsigned int xcc;
    asm volatile("s_getreg_b32 %0, hwreg(HW_REG_XCC_ID)" : "=s"(xcc));
    int pref = (int)((xcc >> 1) & 3);   // 2 XCDs per pass
    int ch = -1, ps = 0;
    #pragma unroll
    for (int a = 0; a < 4; ++a) {
      int p = (pref + a) & 3;
      int c = atomicAdd(&q[p], 1);
      if (c < PASS_CHUNKS) { ch = c; ps = p; break; }
    }
    sChunk = ch; sPass = ps;
  }
  __syncthreads();
  int chunk = sChunk, pass = sPass;
  if (chunk < 0) return;

  int tid = threadIdx.x;
  int lane = tid & 63;
  int sg = lane >> 2;            // node slot 0..15
  int k = lane & 3;              // 8B chunk (features 4k..4k+3 of the slice)
  int slot = (chunk * 4 + (tid >> 6)) * 16 + sg;
  int v = -1, o = 0, d = 1;
  if (slot < N_NODES) {
    v = perm[slot];
    o = row_off[v];
    d = row_off[v + 1] - o;      // >= 1 (self entry)
  }
  int m = d;
  m = max(m, __shfl_xor(m, 4));
  m = max(m, __shfl_xor(m, 8));
  m = max(m, __shfl_xor(m, 16));
  m = max(m, __shfl_xor(m, 32));
  float acc[4] = {0.f, 0.f, 0.f, 0.f};
  const __half* hp = hs + (size_t)pass * N_NODES * FPS + k * 4;
  int dm1 = d - 1;
  int i = 0;
  for (; i + 8 <= m; i += 8) {
    unsigned int e[8];
    uint2 h[8];
    #pragma unroll
    for (int j = 0; j < 8; ++j) e[j] = csr4[o + min(i + j, dm1)];
    #pragma unroll
    for (int j = 0; j < 8; ++j) h[j] = *(const uint2*)(hp + (size_t)(e[j] >> 15) * FPS);
    #pragma unroll
    for (int j = 0; j < 8; ++j) {
      float n = (i + j < d) ? dec_norm(e[j]) : 0.f;
      fma4(acc, n, h[j]);
    }
  }
  for (; i < m; ++i) {
    unsigned int e = csr4[o + min(i, dm1)];
    uint2 h = *(const uint2*)(hp + (size_t)(e >> 15) * FPS);
    float n = (i < d) ? dec_norm(e) : 0.f;
    fma4(acc, n, h);
  }
  if (v >= 0) {
    float4 b = *(const float4*)(bias + pass * FPS + k * 4);
    __half2 q0 = __floats2half2_rn(fmaxf(acc[0] + b.x, 0.f), fmaxf(acc[1] + b.y, 0.f));
    __half2 q1 = __floats2half2_rn(fmaxf(acc[2] + b.z, 0.f), fmaxf(acc[3] + b.w, 0.f));
    unsigned long long r = ((unsigned long long)*(unsigned int*)&q1 << 32) |
                           (unsigned long long)*(unsigned int*)&q0;
    __builtin_nontemporal_store(r, (unsigned long long*)(outs + SL(pass, v, k * 4)));
  }
}

// ---------------------------------------------------------------- pooling + MLP

#define POOL_CHUNK 32

__global__ __launch_bounds__(256) void k_pool(const __half* __restrict__ h,
                                              const int* __restrict__ batch,
                                              float* __restrict__ pooled,
                                              int* __restrict__ pcnt) {
  int wid = threadIdx.x >> 6, lane = threadIdx.x & 63;
  int w = blockIdx.x * (blockDim.x >> 6) + wid;
  int v0 = w * POOL_CHUNK;
  if (v0 >= N_NODES) return;
  int vend = min(v0 + POOL_CHUNK, N_NODES);
  int p = lane >> 4, f = lane & 15;       // feature = p*16+f = lane
  int g = batch[v0];
  float acc = 0.0f;
  int cnt = 0;
  for (int v = v0; v < vend; ++v) {
    int gv = batch[v];
    if (gv != g) {
      atomicAdd(&pooled[g * HID + lane], acc);
      if (lane == 0) atomicAdd(&pcnt[g], cnt);
      g = gv; acc = 0.0f; cnt = 0;
    }
    acc += __half2float(h[SL(p, v, f)]);
    ++cnt;
  }
  atomicAdd(&pooled[g * HID + lane], acc);
  if (lane == 0) atomicAdd(&pcnt[g], cnt);
}

__global__ void k_mlp(const float* __restrict__ pooled, const int* __restrict__ pcnt,
                      const float* __restrict__ fc1w, const float* __restrict__ fc1b,
                      const float* __restrict__ fc2w, const float* __restrict__ fc2b,
                      float* __restrict__ out) {
  int g = threadIdx.x;
  if (g >= NUM_GRAPHS) return;
  float inv = 1.0f / fmaxf((float)pcnt[g], 1.0f);
  float hid[10];
  #pragma unroll
  for (int j = 0; j < 10; ++j) hid[j] = fc1b[j];
  for (int k = 0; k < HID; ++k) {
    float p = pooled[g * HID + k] * inv;
    #pragma unroll
    for (int j = 0; j < 10; ++j) hid[j] += p * fc1w[k * 10 + j];
  }
  float o = fc2b[0];
  #pragma unroll
  for (int j = 0; j < 10; ++j) o += fmaxf(hid[j], 0.0f) * fc2w[j];
  out[g] = o;
}

// ---------------------------------------------------------------- launch

extern "C" void kernel_launch(void* const* d_in, const int* in_sizes, int n_in,
                              void* d_out, int out_size, void* d_ws, size_t ws_size,
                              hipStream_t stream) {
  const float* x    = (const float*)d_in[0];
  const int*   ei   = (const int*)d_in[1];      // [2, E]
  const int*   batch= (const int*)d_in[2];
  const float* W1   = (const float*)d_in[3];
  const float* b1   = (const float*)d_in[4];
  const float* W2   = (const float*)d_in[5];
  const float* b2   = (const float*)d_in[6];
  const float* W3   = (const float*)d_in[7];
  const float* b3   = (const float*)d_in[8];
  const float* fc1w = (const float*)d_in[9];
  const float* fc1b = (const float*)d_in[10];
  const float* fc2w = (const float*)d_in[11];
  const float* fc2b = (const float*)d_in[12];

  const int* e_src = ei;
  const int* e_dst = ei + N_EDGES;

  // ---- workspace layout
  char* ws = (char*)d_ws;
  auto alignup = [](size_t o, size_t a) { return (o + a - 1) / a * a; };
  size_t off = 0;
  int*   H      = (int*)(ws + off);  off += (size_t)NB * NB * 4;   // fully overwritten by b1a
  int*   pcnt   = (int*)(ws + off);  off += 128 * 4;               // zeroed by dscan
  float* pooled = (float*)(ws + off); off += 8192 * 4;             // zeroed by dscan
  int*   dbins  = (int*)(ws + off);  off += 256 * 4;               // zeroed by rowscan
  int*   S      = (int*)(ws + off);  off += NB * 4;
  int*   bstart = (int*)(ws + off);  off += (NB + 1) * 4;
  int*   dpos   = (int*)(ws + off);  off += 256 * 4;
  int*   qcnt   = (int*)(ws + off);  off += 16 * 4;        off = alignup(off, 256);
  int*   OT     = (int*)(ws + off);  off += (size_t)NB * NB * 4;          off = alignup(off, 256);
  int*   row_off= (int*)(ws + off);  off += (size_t)(N_NODES + 1) * 4;    off = alignup(off, 256);
  float* dinv   = (float*)(ws + off); off += (size_t)N_NODES * 4;         off = alignup(off, 256);
  int*   perm   = (int*)(ws + off);  off += (size_t)N_NODES * 4;          off = alignup(off, 256);
  unsigned int* csr4 = (unsigned int*)(ws + off); off += (size_t)CSR_TOT * 4; off = alignup(off, 256);
  __half* h_a   = (__half*)(ws + off); off += (size_t)N_NODES * HID * 2;  off = alignup(off, 256);
  // staged (build phase) and h_b (layer phase) are disjoint in time -> union
  int2*  staged = (int2*)(ws + off);
  __half* h_b   = (__half*)(ws + off); off += (size_t)N_EDGES * 8;
  (void)ws_size; (void)in_sizes; (void)n_in; (void)out_size;

  const int TB = 256;
  const int NGRID = (N_NODES + TB - 1) / TB;   // 391
  // ---- build
  k_b1a    <<<NB, TB, 0, stream>>>(e_dst, H);
  k_colsum <<<NB, TB, 0, stream>>>(H, S);
  k_rowscan<<<NB, 512, 0, stream>>>(H, S, bstart, OT, dbins);
  k_b1b    <<<NB, TB, 0, stream>>>(e_src, e_dst, OT, staged);
  k_b2a    <<<NBU, TB, 0, stream>>>(staged, bstart, row_off, dinv, dbins);
  k_b2b    <<<NBU, TB, 0, stream>>>(staged, bstart, row_off, dinv, csr4);
  // ---- degree sort (ascending) + queue/pool zeroing
  k_dscan  <<<1, TB, 0, stream>>>(dbins, dpos, pooled, pcnt, qcnt);
  k_dperm  <<<NGRID, TB, 0, stream>>>(row_off, dpos, perm);

  const int GEMM_GRID = (N_NODES + 63) / 64;     // 1563
  const int AGGS_GRID = 4 * PASS_CHUNKS;         // 6252 (4 passes x 1563 chunks)

  // ---- layers (gemm first: agg(h@W) == agg(h)@W, aggregation is linear)
  k_gemm_f32<<<GEMM_GRID, TB, 0, stream>>>(x, W1, h_a);
  k_aggs   <<<AGGS_GRID, TB, 0, stream>>>(h_a, row_off, csr4, perm, b1, h_b, qcnt + 0);
  k_gemm   <<<GEMM_GRID, TB, 0, stream>>>(h_b, W2, h_a);
  k_aggs   <<<AGGS_GRID, TB, 0, stream>>>(h_a, row_off, csr4, perm, b2, h_b, qcnt + 4);
  k_gemm   <<<GEMM_GRID, TB, 0, stream>>>(h_b, W3, h_a);
  k_aggs   <<<AGGS_GRID, TB, 0, stream>>>(h_a, row_off, csr4, perm, b3, h_b, qcnt + 8);

  // ---- pool + MLP
  const int POOL_GRID = ((N_NODES + POOL_CHUNK - 1) / POOL_CHUNK + 3) / 4;
  k_pool<<<POOL_GRID, TB, 0, stream>>>(h_b, batch, pooled, pcnt);
  k_mlp <<<1, 128, 0, stream>>>(pooled, pcnt, fc1w, fc1b, fc2w, fc2b, (float*)d_out);
}

// Round 15
// 256.416 us; speedup vs baseline: 1.8160x; 1.8160x over previous
//
#include <hip/hip_runtime.h>
#include <hip/hip_fp16.h>

#define N_NODES   100000
#define N_EDGES   1600000
#define NUM_GRAPHS 128
#define HID       64

#define NB   512          // buckets (node-space partitions)
#define NPB  196          // nodes per bucket (<256 -> local id fits 8 bits)
#define NBU  511          // used buckets
#define CPE  3125         // edges per binning chunk
#define CSR_TOT (N_EDGES + N_NODES)   // CSR includes one self entry per node

// ---------------------------------------------------------------- bucketed CSR build

__global__ __launch_bounds__(256) void k_b1a(const int* __restrict__ dst, int* __restrict__ H) {
  __shared__ int hist[NB];
  int w = blockIdx.x, t = threadIdx.x;
  for (int b = t; b < NB; b += 256) hist[b] = 0;
  __syncthreads();
  int e0 = w * CPE;
  for (int i = t; i < CPE; i += 256)
    atomicAdd(&hist[dst[e0 + i] / NPB], 1);
  __syncthreads();
  for (int b = t; b < NB; b += 256) H[w * NB + b] = hist[b];
}

__global__ __launch_bounds__(256) void k_colsum(const int* __restrict__ H, int* __restrict__ S) {
  __shared__ int red[256];
  int b = blockIdx.x, t = threadIdx.x;
  red[t] = H[t * NB + b] + H[(t + 256) * NB + b];
  __syncthreads();
  for (int d = 128; d > 0; d >>= 1) { if (t < d) red[t] += red[t + d]; __syncthreads(); }
  if (t == 0) S[b] = red[0];
}

__global__ __launch_bounds__(512) void k_rowscan(const int* __restrict__ H,
                                                 const int* __restrict__ S,
                                                 int* __restrict__ bstart,
                                                 int* __restrict__ OT,
                                                 int* __restrict__ dbins) {
  __shared__ int sb[NB];
  __shared__ int sc[NB];
  int b = blockIdx.x, t = threadIdx.x;
  if (t < 256) dbins[t] = 0;
  int sv = S[t];
  sb[t] = sv; __syncthreads();
  for (int d = 1; d < NB; d <<= 1) {
    int x = (t >= d) ? sb[t - d] : 0; __syncthreads();
    sb[t] += x; __syncthreads();
  }
  int bst = sb[b] - S[b];
  if (t == 0) bstart[b] = bst;
  if (b == NB - 1 && t == 0) bstart[NB] = sb[NB - 1];
  int v = H[t * NB + b];
  sc[t] = v; __syncthreads();
  for (int d = 1; d < NB; d <<= 1) {
    int x = (t >= d) ? sc[t - d] : 0; __syncthreads();
    sc[t] += x; __syncthreads();
  }
  OT[b * NB + t] = bst + sc[t] - v;
}

// B1b: bin edges into bucket-contiguous staging. 4B staged entry:
// src (17b) << 8 | local_dst (8b, < NPB=196). Halves staging traffic vs int2.
__global__ __launch_bounds__(256) void k_b1b(const int* __restrict__ src,
                                             const int* __restrict__ dst,
                                             const int* __restrict__ OT,
                                             unsigned int* __restrict__ staged) {
  __shared__ int pos[NB];
  int w = blockIdx.x, t = threadIdx.x;
  for (int b = t; b < NB; b += 256) pos[b] = OT[b * NB + w];
  __syncthreads();
  int e0 = w * CPE;
  for (int i = t; i < CPE; i += 256) {
    int s = src[e0 + i], d = dst[e0 + i];
    int bk = d / NPB;
    int p = atomicAdd(&pos[bk], 1);
    staged[p] = ((unsigned int)s << 8) | (unsigned int)(d - bk * NPB);
  }
}

// B2a: LDS node counts -> monotone row_off + dinv + LDS-aggregated degree hist (ascending).
__global__ __launch_bounds__(256) void k_b2a(const unsigned int* __restrict__ staged,
                                             const int* __restrict__ bstart,
                                             int* __restrict__ row_off,
                                             float* __restrict__ dinv,
                                             int* __restrict__ dbins) {
  __shared__ int cnt[256];
  __shared__ int sc[256];
  __shared__ int hb[256];
  int b = blockIdx.x, t = threadIdx.x;
  int nloc = min(NPB, N_NODES - b * NPB);
  cnt[t] = 0;
  hb[t] = 0;
  __syncthreads();
  int s0 = bstart[b], s1 = bstart[b + 1];
  for (int i = s0 + t; i < s1; i += 256)
    atomicAdd(&cnt[staged[i] & 0xffu], 1);
  __syncthreads();
  if (t < nloc) atomicAdd(&hb[min(cnt[t] + 1, 255)], 1);
  int v = (t < nloc) ? cnt[t] + 1 : 0;
  sc[t] = v; __syncthreads();
  for (int d = 1; d < 256; d <<= 1) {
    int x = (t >= d) ? sc[t - d] : 0; __syncthreads();
    sc[t] += x; __syncthreads();
  }
  if (t < nloc) {
    int g = b * NPB + t;
    row_off[g] = bstart[b] + b * NPB + (sc[t] - v);
    dinv[g] = rsqrtf((float)(cnt[t] + 1));
  }
  __syncthreads();
  if (hb[t] > 0) atomicAdd(&dbins[t], hb[t]);
  if (b == 0 && t == 0) row_off[N_NODES] = CSR_TOT;
}

// 4B CSR entry: src (17 bits) << 15 | fp16(norm) sans sign (15 bits). norm>0.
__device__ __forceinline__ unsigned int enc_csr(int s, float n) {
  unsigned short bits = __half_as_ushort(__float2half_rn(n));
  return ((unsigned int)s << 15) | (unsigned int)(bits & 0x7fff);
}

__global__ __launch_bounds__(256) void k_b2b(const unsigned int* __restrict__ staged,
                                             const int* __restrict__ bstart,
                                             const int* __restrict__ row_off,
                                             const float* __restrict__ dinv,
                                             unsigned int* __restrict__ csr4) {
  __shared__ int pos[NPB];
  __shared__ float dl[NPB];
  int b = blockIdx.x, t = threadIdx.x;
  int nloc = min(NPB, N_NODES - b * NPB);
  if (t < nloc) {
    int g = b * NPB + t;
    int ro = row_off[g];
    float dv = dinv[g];
    csr4[ro] = enc_csr(g, dv * dv);   // self-loop entry
    pos[t] = ro + 1;
    dl[t] = dv;
  }
  __syncthreads();
  int s0 = bstart[b], s1 = bstart[b + 1];
  for (int i = s0 + t; i < s1; i += 256) {
    unsigned int e = staged[i];
    int l = (int)(e & 0xffu);
    int s = (int)(e >> 8);
    int p = atomicAdd(&pos[l], 1);
    csr4[p] = enc_csr(s, dl[l] * dinv[s]);
  }
}

// ---------------------------------------------------------------- degree sort (ascending)

__global__ __launch_bounds__(256) void k_dscan(const int* __restrict__ dbins,
                                               int* __restrict__ dpos,
                                               float* __restrict__ pooled,
                                               int* __restrict__ pcnt) {
  __shared__ int sc[256];
  int t = threadIdx.x;
  #pragma unroll
  for (int i = 0; i < 32; ++i) pooled[i * 256 + t] = 0.f;
  if (t < 128) pcnt[t] = 0;
  int v = dbins[t];
  sc[t] = v; __syncthreads();
  for (int d = 1; d < 256; d <<= 1) {
    int x = (t >= d) ? sc[t - d] : 0; __syncthreads();
    sc[t] += x; __syncthreads();
  }
  dpos[t] = sc[t] - v;
}

__global__ __launch_bounds__(256) void k_dperm(const int* __restrict__ row_off,
                                               int* __restrict__ dpos,
                                               int* __restrict__ perm) {
  __shared__ int cnt[256];
  __shared__ int sbase[256];
  int t = threadIdx.x;
  cnt[t] = 0;
  __syncthreads();
  int v = blockIdx.x * 256 + t;
  int bin = 0, rank = 0;
  if (v < N_NODES) {
    bin = min(row_off[v + 1] - row_off[v], 255);   // ascending
    rank = atomicAdd(&cnt[bin], 1);
  }
  __syncthreads();
  if (cnt[t] > 0) sbase[t] = atomicAdd(&dpos[t], cnt[t]);
  __syncthreads();
  if (v < N_NODES) perm[sbase[bin] + rank] = v;
}

// ---------------------------------------------------------------- dense GEMM (row-major fp16 out)
// layer 1 reads f32 input directly; layers 2-3 read fp16.

template <typename T>
__device__ __forceinline__ void gemm_body(const T* __restrict__ A,
                                          const float* __restrict__ W,
                                          __half* __restrict__ C) {
  __shared__ float sW[64 * 64];
  __shared__ float sA[64][65];
  int tid = threadIdx.x;
  #pragma unroll
  for (int i = tid; i < 1024; i += 256)
    ((float4*)sW)[i] = ((const float4*)W)[i];
  int row0 = blockIdx.x * 64;
  #pragma unroll
  for (int i = tid; i < 1024; i += 256) {
    int r = i >> 4, c4 = (i & 15) << 2;
    int row = row0 + r;
    if (row < N_NODES) {
      const T* a = A + (size_t)row * 64 + c4;
      sA[r][c4 + 0] = (float)a[0]; sA[r][c4 + 1] = (float)a[1];
      sA[r][c4 + 2] = (float)a[2]; sA[r][c4 + 3] = (float)a[3];
    } else {
      sA[r][c4 + 0] = 0.f; sA[r][c4 + 1] = 0.f; sA[r][c4 + 2] = 0.f; sA[r][c4 + 3] = 0.f;
    }
  }
  __syncthreads();
  int tr = (tid >> 4) << 2;
  int tc = (tid & 15) << 2;
  float acc[4][4];
  #pragma unroll
  for (int i = 0; i < 4; ++i)
    #pragma unroll
    for (int j = 0; j < 4; ++j) acc[i][j] = 0.f;
  #pragma unroll 8
  for (int k = 0; k < 64; ++k) {
    float4 w = *(const float4*)&sW[k * 64 + tc];
    float a0 = sA[tr + 0][k], a1 = sA[tr + 1][k], a2 = sA[tr + 2][k], a3 = sA[tr + 3][k];
    acc[0][0] += a0 * w.x; acc[0][1] += a0 * w.y; acc[0][2] += a0 * w.z; acc[0][3] += a0 * w.w;
    acc[1][0] += a1 * w.x; acc[1][1] += a1 * w.y; acc[1][2] += a1 * w.z; acc[1][3] += a1 * w.w;
    acc[2][0] += a2 * w.x; acc[2][1] += a2 * w.y; acc[2][2] += a2 * w.z; acc[2][3] += a2 * w.w;
    acc[3][0] += a3 * w.x; acc[3][1] += a3 * w.y; acc[3][2] += a3 * w.z; acc[3][3] += a3 * w.w;
  }
  #pragma unroll
  for (int i = 0; i < 4; ++i) {
    int row = row0 + tr + i;
    if (row < N_NODES) {
      *(__half2*)(C + (size_t)row * 64 + tc)     = __floats2half2_rn(acc[i][0], acc[i][1]);
      *(__half2*)(C + (size_t)row * 64 + tc + 2) = __floats2half2_rn(acc[i][2], acc[i][3]);
    }
  }
}

__global__ __launch_bounds__(256) void k_gemm_f32(const float* __restrict__ A,
                                                  const float* __restrict__ W,
                                                  __half* __restrict__ C) {
  gemm_body<float>(A, W, C);
}

__global__ __launch_bounds__(256) void k_gemm(const __half* __restrict__ A,
                                              const float* __restrict__ W,
                                              __half* __restrict__ C) {
  gemm_body<__half>(A, W, C);
}

// ---------------------------------------------------------------- aggregation (R12 proven form)
// 8 nodes/wave (degree-sorted ASC), 8 lanes/node, 16B per lane, unroll 8.
// CSR loads PLAIN (nt on sub-line consumption self-evicts: R10/R11 +11MB FETCH).

__device__ __forceinline__ void fma8(float* acc, float n, uint4 h) {
  __half2 u0 = *(__half2*)&h.x, u1 = *(__half2*)&h.y;
  __half2 u2 = *(__half2*)&h.z, u3 = *(__half2*)&h.w;
  float2 f0 = __half22float2(u0), f1 = __half22float2(u1);
  float2 f2 = __half22float2(u2), f3 = __half22float2(u3);
  acc[0] = fmaf(n, f0.x, acc[0]); acc[1] = fmaf(n, f0.y, acc[1]);
  acc[2] = fmaf(n, f1.x, acc[2]); acc[3] = fmaf(n, f1.y, acc[3]);
  acc[4] = fmaf(n, f2.x, acc[4]); acc[5] = fmaf(n, f2.y, acc[5]);
  acc[6] = fmaf(n, f3.x, acc[6]); acc[7] = fmaf(n, f3.y, acc[7]);
}

__device__ __forceinline__ float dec_norm(unsigned int e) {
  return __half2float(__ushort_as_half((unsigned short)(e & 0x7fffu)));
}

__global__ __launch_bounds__(256) void k_agg(const __half* __restrict__ hw,
                                             const int* __restrict__ row_off,
                                             const unsigned int* __restrict__ csr4,
                                             const int* __restrict__ perm,
                                             const float* __restrict__ bias,
                                             __half* __restrict__ out) {
  int tid = threadIdx.x;
  int lane = tid & 63;
  int sg = lane >> 3;            // subgroup = node slot within wave
  int k = lane & 7;              // 16B chunk (8 features) within row
  int slot = (blockIdx.x * 4 + (tid >> 6)) * 8 + sg;
  int v = -1, o = 0, d = 1;
  if (slot < N_NODES) {
    v = perm[slot];
    o = row_off[v];
    d = row_off[v + 1] - o;      // >= 1 (self entry)
  }
  int m = d;
  m = max(m, __shfl_xor(m, 8));
  m = max(m, __shfl_xor(m, 16));
  m = max(m, __shfl_xor(m, 32));
  float acc[8];
  #pragma unroll
  for (int j = 0; j < 8; ++j) acc[j] = 0.f;
  const __half* hk = hw + k * 8;
  int dm1 = d - 1;
  int i = 0;
  for (; i + 8 <= m; i += 8) {
    unsigned int e[8];
    uint4 h[8];
    #pragma unroll
    for (int j = 0; j < 8; ++j) e[j] = csr4[o + min(i + j, dm1)];
    #pragma unroll
    for (int j = 0; j < 8; ++j) h[j] = *(const uint4*)(hk + (size_t)(e[j] >> 15) * 64);
    #pragma unroll
    for (int j = 0; j < 8; ++j) {
      float n = (i + j < d) ? dec_norm(e[j]) : 0.f;
      fma8(acc, n, h[j]);
    }
  }
  for (; i < m; ++i) {
    unsigned int e = csr4[o + min(i, dm1)];
    uint4 h = *(const uint4*)(hk + (size_t)(e >> 15) * 64);
    float n = (i < d) ? dec_norm(e) : 0.f;
    fma8(acc, n, h);
  }
  if (v >= 0) {
    float4 b0 = *(const float4*)(bias + k * 8);
    float4 b1 = *(const float4*)(bias + k * 8 + 4);
    __half2 q0 = __floats2half2_rn(fmaxf(acc[0] + b0.x, 0.f), fmaxf(acc[1] + b0.y, 0.f));
    __half2 q1 = __floats2half2_rn(fmaxf(acc[2] + b0.z, 0.f), fmaxf(acc[3] + b0.w, 0.f));
    __half2 q2 = __floats2half2_rn(fmaxf(acc[4] + b1.x, 0.f), fmaxf(acc[5] + b1.y, 0.f));
    __half2 q3 = __floats2half2_rn(fmaxf(acc[6] + b1.z, 0.f), fmaxf(acc[7] + b1.w, 0.f));
    uint4 r;
    r.x = *(unsigned int*)&q0; r.y = *(unsigned int*)&q1;
    r.z = *(unsigned int*)&q2; r.w = *(unsigned int*)&q3;
    *(uint4*)(out + (size_t)v * HID + k * 8) = r;
  }
}

// ---------------------------------------------------------------- pooling + MLP

#define POOL_CHUNK 32

__global__ __launch_bounds__(256) void k_pool(const __half* __restrict__ h,
                                              const int* __restrict__ batch,
                                              float* __restrict__ pooled,
                                              int* __restrict__ pcnt) {
  int wid = threadIdx.x >> 6, lane = threadIdx.x & 63;
  int w = blockIdx.x * (blockDim.x >> 6) + wid;
  int v0 = w * POOL_CHUNK;
  if (v0 >= N_NODES) return;
  int vend = min(v0 + POOL_CHUNK, N_NODES);
  int g = batch[v0];
  float acc = 0.0f;
  int cnt = 0;
  for (int v = v0; v < vend; ++v) {
    int gv = batch[v];
    if (gv != g) {
      atomicAdd(&pooled[g * HID + lane], acc);
      if (lane == 0) atomicAdd(&pcnt[g], cnt);
      g = gv; acc = 0.0f; cnt = 0;
    }
    acc += __half2float(h[(size_t)v * HID + lane]);
    ++cnt;
  }
  atomicAdd(&pooled[g * HID + lane], acc);
  if (lane == 0) atomicAdd(&pcnt[g], cnt);
}

__global__ void k_mlp(const float* __restrict__ pooled, const int* __restrict__ pcnt,
                      const float* __restrict__ fc1w, const float* __restrict__ fc1b,
                      const float* __restrict__ fc2w, const float* __restrict__ fc2b,
                      float* __restrict__ out) {
  int g = threadIdx.x;
  if (g >= NUM_GRAPHS) return;
  float inv = 1.0f / fmaxf((float)pcnt[g], 1.0f);
  float hid[10];
  #pragma unroll
  for (int j = 0; j < 10; ++j) hid[j] = fc1b[j];
  for (int k = 0; k < HID; ++k) {
    float p = pooled[g * HID + k] * inv;
    #pragma unroll
    for (int j = 0; j < 10; ++j) hid[j] += p * fc1w[k * 10 + j];
  }
  float o = fc2b[0];
  #pragma unroll
  for (int j = 0; j < 10; ++j) o += fmaxf(hid[j], 0.0f) * fc2w[j];
  out[g] = o;
}

// ---------------------------------------------------------------- launch

extern "C" void kernel_launch(void* const* d_in, const int* in_sizes, int n_in,
                              void* d_out, int out_size, void* d_ws, size_t ws_size,
                              hipStream_t stream) {
  const float* x    = (const float*)d_in[0];
  const int*   ei   = (const int*)d_in[1];      // [2, E]
  const int*   batch= (const int*)d_in[2];
  const float* W1   = (const float*)d_in[3];
  const float* b1   = (const float*)d_in[4];
  const float* W2   = (const float*)d_in[5];
  const float* b2   = (const float*)d_in[6];
  const float* W3   = (const float*)d_in[7];
  const float* b3   = (const float*)d_in[8];
  const float* fc1w = (const float*)d_in[9];
  const float* fc1b = (const float*)d_in[10];
  const float* fc2w = (const float*)d_in[11];
  const float* fc2b = (const float*)d_in[12];

  const int* e_src = ei;
  const int* e_dst = ei + N_EDGES;

  // ---- workspace layout
  char* ws = (char*)d_ws;
  auto alignup = [](size_t o, size_t a) { return (o + a - 1) / a * a; };
  size_t off = 0;
  int*   H      = (int*)(ws + off);  off += (size_t)NB * NB * 4;   // fully overwritten by b1a
  int*   pcnt   = (int*)(ws + off);  off += 128 * 4;               // zeroed by dscan
  float* pooled = (float*)(ws + off); off += 8192 * 4;             // zeroed by dscan
  int*   dbins  = (int*)(ws + off);  off += 256 * 4;               // zeroed by rowscan
  int*   S      = (int*)(ws + off);  off += NB * 4;
  int*   bstart = (int*)(ws + off);  off += (NB + 1) * 4;
  int*   dpos   = (int*)(ws + off);  off += 256 * 4;       off = alignup(off, 256);
  int*   OT     = (int*)(ws + off);  off += (size_t)NB * NB * 4;          off = alignup(off, 256);
  int*   row_off= (int*)(ws + off);  off += (size_t)(N_NODES + 1) * 4;    off = alignup(off, 256);
  float* dinv   = (float*)(ws + off); off += (size_t)N_NODES * 4;         off = alignup(off, 256);
  int*   perm   = (int*)(ws + off);  off += (size_t)N_NODES * 4;          off = alignup(off, 256);
  unsigned int* csr4 = (unsigned int*)(ws + off); off += (size_t)CSR_TOT * 4; off = alignup(off, 256);
  __half* h_a   = (__half*)(ws + off); off += (size_t)N_NODES * HID * 2;  off = alignup(off, 256);
  // staged (build phase) and h_b (layer phase) are disjoint in time -> union
  unsigned int* staged = (unsigned int*)(ws + off);
  __half* h_b   = (__half*)(ws + off); off += (size_t)N_EDGES * 8;
  (void)ws_size; (void)in_sizes; (void)n_in; (void)out_size;

  const int TB = 256;
  const int NGRID = (N_NODES + TB - 1) / TB;   // 391
  // ---- build
  k_b1a    <<<NB, TB, 0, stream>>>(e_dst, H);
  k_colsum <<<NB, TB, 0, stream>>>(H, S);
  k_rowscan<<<NB, 512, 0, stream>>>(H, S, bstart, OT, dbins);
  k_b1b    <<<NB, TB, 0, stream>>>(e_src, e_dst, OT, staged);
  k_b2a    <<<NBU, TB, 0, stream>>>(staged, bstart, row_off, dinv, dbins);
  k_b2b    <<<NBU, TB, 0, stream>>>(staged, bstart, row_off, dinv, csr4);
  // ---- degree sort (ascending)
  k_dscan  <<<1, TB, 0, stream>>>(dbins, dpos, pooled, pcnt);
  k_dperm  <<<NGRID, TB, 0, stream>>>(row_off, dpos, perm);

  const int GEMM_GRID = (N_NODES + 63) / 64;   // 1563
  const int AGG_GRID  = (N_NODES + 31) / 32;   // 3125 (32 nodes per block)

  // ---- layers (gemm first: agg(h@W) == agg(h)@W, aggregation is linear)
  k_gemm_f32<<<GEMM_GRID, TB, 0, stream>>>(x, W1, h_a);
  k_agg    <<<AGG_GRID, TB, 0, stream>>>(h_a, row_off, csr4, perm, b1, h_b);
  k_gemm   <<<GEMM_GRID, TB, 0, stream>>>(h_b, W2, h_a);
  k_agg    <<<AGG_GRID, TB, 0, stream>>>(h_a, row_off, csr4, perm, b2, h_b);
  k_gemm   <<<GEMM_GRID, TB, 0, stream>>>(h_b, W3, h_a);
  k_agg    <<<AGG_GRID, TB, 0, stream>>>(h_a, row_off, csr4, perm, b3, h_b);

  // ---- pool + MLP
  const int POOL_GRID = ((N_NODES + POOL_CHUNK - 1) / POOL_CHUNK + 3) / 4;
  k_pool<<<POOL_GRID, TB, 0, stream>>>(h_b, batch, pooled, pcnt);
  k_mlp <<<1, 128, 0, stream>>>(pooled, pcnt, fc1w, fc1b, fc2w, fc2b, (float*)d_out);
}